// Round 1
// baseline (292.207 us; speedup 1.0000x reference)
//
#include <hip/hip_runtime.h>

#define MD 1024
#define L 128
#define BH 32
#define ROWS 512
#define LN_EPS 1e-5f

// ---------------------------------------------------------------------------
// Generic fp32 GEMM: out[r][c] = sum_m in[r][m] * W[c][m] + bias[c]
// (i.e. out = in @ W.T + bias). Tile 64x64, 256 threads, 4x4 per thread.
// ---------------------------------------------------------------------------
__device__ __forceinline__ void gemm_body(const float* __restrict__ in,
                                          const float* __restrict__ W,
                                          const float* __restrict__ bias,
                                          float* __restrict__ out) {
  __shared__ __align__(16) float As[64][36];
  __shared__ __align__(16) float Bs[64][36];
  const int t = threadIdx.x;
  const int row0 = blockIdx.x * 64;
  const int col0 = blockIdx.y * 64;
  const int tx = t & 15;
  const int ty = (t >> 4) & 15;
  float acc[4][4] = {{0.f, 0.f, 0.f, 0.f}, {0.f, 0.f, 0.f, 0.f},
                     {0.f, 0.f, 0.f, 0.f}, {0.f, 0.f, 0.f, 0.f}};
  const int lr0 = t >> 3;        // 0..31
  const int lk = (t & 7) * 4;    // 0,4,..,28

  for (int k0 = 0; k0 < MD; k0 += 32) {
    float4 a0 = *(const float4*)&in[(size_t)(row0 + lr0) * MD + k0 + lk];
    float4 a1 = *(const float4*)&in[(size_t)(row0 + lr0 + 32) * MD + k0 + lk];
    float4 b0 = *(const float4*)&W[(size_t)(col0 + lr0) * MD + k0 + lk];
    float4 b1 = *(const float4*)&W[(size_t)(col0 + lr0 + 32) * MD + k0 + lk];
    __syncthreads();
    *(float4*)&As[lr0][lk] = a0;
    *(float4*)&As[lr0 + 32][lk] = a1;
    *(float4*)&Bs[lr0][lk] = b0;
    *(float4*)&Bs[lr0 + 32][lk] = b1;
    __syncthreads();
#pragma unroll
    for (int kk = 0; kk < 32; kk++) {
      float a[4], b[4];
#pragma unroll
      for (int m = 0; m < 4; m++) a[m] = As[ty + 16 * m][kk];
#pragma unroll
      for (int n = 0; n < 4; n++) b[n] = Bs[tx + 16 * n][kk];
#pragma unroll
      for (int m = 0; m < 4; m++)
#pragma unroll
        for (int n = 0; n < 4; n++) acc[m][n] += a[m] * b[n];
    }
  }
#pragma unroll
  for (int m = 0; m < 4; m++) {
    const int rr = row0 + ty + 16 * m;
#pragma unroll
    for (int n = 0; n < 4; n++) {
      const int cc = col0 + tx + 16 * n;
      out[(size_t)rr * MD + cc] = acc[m][n] + bias[cc];
    }
  }
}

__global__ __launch_bounds__(256) void qkv_gemm(
    const float* __restrict__ query, const float* __restrict__ key,
    const float* __restrict__ value, const float* __restrict__ Wq,
    const float* __restrict__ Wk, const float* __restrict__ Wv,
    const float* __restrict__ bq, const float* __restrict__ bk,
    const float* __restrict__ bv, float* __restrict__ qo,
    float* __restrict__ ko, float* __restrict__ vo) {
  const float* in;
  const float* W;
  const float* bias;
  float* out;
  if (blockIdx.z == 0) { in = query; W = Wq; bias = bq; out = qo; }
  else if (blockIdx.z == 1) { in = key; W = Wk; bias = bk; out = ko; }
  else { in = value; W = Wv; bias = bv; out = vo; }
  gemm_body(in, W, bias, out);
}

__global__ __launch_bounds__(256) void o_gemm(const float* __restrict__ in,
                                              const float* __restrict__ W,
                                              const float* __restrict__ bias,
                                              float* __restrict__ out) {
  gemm_body(in, W, bias, out);
}

// ---------------------------------------------------------------------------
// Per (g, i): attn logits = q . (k + rq), softmax over j -> attn out;
// v2[g,i,j] = v[g,i,j] + v . rv[g,i,j,:]. Streams rq, rv (the 512 MB).
// 256 threads = 4 waves; each wave handles 2 j rows per iteration via
// 32-lane-half float4 coalesced loads + butterfly reduce.
// ---------------------------------------------------------------------------
__global__ __launch_bounds__(256) void rel_fused(
    const float* __restrict__ q, const float* __restrict__ k,
    const float* __restrict__ v, const float* __restrict__ rq,
    const float* __restrict__ rv, float* __restrict__ attn,
    float* __restrict__ v2) {
  const int g = blockIdx.x;  // 0..31
  const int i = blockIdx.y;  // 0..127
  const int t = threadIdx.x;
  const int w = t >> 6;
  const int l = t & 63;
  const int l32 = l & 31;
  const int half = l >> 5;
  __shared__ float logits[L];

  const size_t gi = (size_t)g * L + i;
  const float* qrow = q + (size_t)g * (L * 128) + (size_t)i * 128;
  const float* vrow = v + (size_t)g * (L * 128) + (size_t)i * 128;
  const float4 qf = *(const float4*)&qrow[l32 * 4];
  const float4 vf = *(const float4*)&vrow[l32 * 4];
  const float* rqp = rq + gi * (L * 128);
  const float* rvp = rv + gi * (L * 128);
  const float* kg = k + (size_t)g * (L * 128);

#pragma unroll 4
  for (int p = 0; p < 16; p++) {
    const int j = ((w * 16 + p) << 1) | half;
    const float4 rr = *(const float4*)&rqp[j * 128 + l32 * 4];
    const float4 kk = *(const float4*)&kg[j * 128 + l32 * 4];
    float s = qf.x * (rr.x + kk.x) + qf.y * (rr.y + kk.y) +
              qf.z * (rr.z + kk.z) + qf.w * (rr.w + kk.w);
    s += __shfl_xor(s, 1);
    s += __shfl_xor(s, 2);
    s += __shfl_xor(s, 4);
    s += __shfl_xor(s, 8);
    s += __shfl_xor(s, 16);
    if (l32 == 0) logits[j] = s * 0.25f;  // scale = (128//8)^-0.5 = 0.25
  }

#pragma unroll 4
  for (int p = 0; p < 16; p++) {
    const int j = ((w * 16 + p) << 1) | half;
    const float4 rr = *(const float4*)&rvp[j * 128 + l32 * 4];
    float s = vf.x * rr.x + vf.y * rr.y + vf.z * rr.z + vf.w * rr.w;
    s += __shfl_xor(s, 1);
    s += __shfl_xor(s, 2);
    s += __shfl_xor(s, 4);
    s += __shfl_xor(s, 8);
    s += __shfl_xor(s, 16);
    if (l32 == 0) v2[gi * 128 + j] = vrow[j] + s;
  }

  __syncthreads();
  if (w == 0) {
    const float x0 = logits[l];
    const float x1 = logits[l + 64];
    float m = fmaxf(x0, x1);
#pragma unroll
    for (int mask = 1; mask <= 32; mask <<= 1) m = fmaxf(m, __shfl_xor(m, mask));
    const float e0 = __expf(x0 - m);
    const float e1 = __expf(x1 - m);
    float ssum = e0 + e1;
#pragma unroll
    for (int mask = 1; mask <= 32; mask <<= 1) ssum += __shfl_xor(ssum, mask);
    const float inv = 1.0f / ssum;
    attn[gi * 128 + l] = e0 * inv;
    attn[gi * 128 + l + 64] = e1 * inv;
  }
}

// ---------------------------------------------------------------------------
// context[g,i,:] = sum_j attn[g,i,j] * v2[g,j,:]
// ---------------------------------------------------------------------------
__global__ __launch_bounds__(256) void context_k(const float* __restrict__ attn,
                                                 const float* __restrict__ v2,
                                                 float* __restrict__ ctx) {
  const int g = blockIdx.x;
  const int i = blockIdx.y;
  const int t = threadIdx.x;
  const int dd = t & 127;
  const int h = t >> 7;
  __shared__ float arow[L];
  __shared__ float part[128];
  const size_t gi = (size_t)g * L + i;
  if (t < L) arow[t] = attn[gi * 128 + t];
  __syncthreads();
  float acc = 0.f;
  const float* v2g = v2 + (size_t)g * (L * 128);
#pragma unroll 8
  for (int j = h * 64; j < h * 64 + 64; j++)
    acc = fmaf(arow[j], v2g[j * 128 + dd], acc);
  if (h == 1) part[dd] = acc;
  __syncthreads();
  if (h == 0) ctx[gi * 128 + dd] = acc + part[dd];
}

// ---------------------------------------------------------------------------
// out = LayerNorm(pre + residual) * gamma + beta, per row of 1024.
// ---------------------------------------------------------------------------
__global__ __launch_bounds__(256) void resid_ln(const float* __restrict__ pre,
                                                const float* __restrict__ resid,
                                                const float* __restrict__ gamma,
                                                const float* __restrict__ beta,
                                                float* __restrict__ out) {
  const int r = blockIdx.x;
  const int t = threadIdx.x;
  const float4 p = *(const float4*)&pre[(size_t)r * MD + t * 4];
  const float4 rs = *(const float4*)&resid[(size_t)r * MD + t * 4];
  float4 x;
  x.x = p.x + rs.x; x.y = p.y + rs.y; x.z = p.z + rs.z; x.w = p.w + rs.w;
  float s = x.x + x.y + x.z + x.w;
  float ss = x.x * x.x + x.y * x.y + x.z * x.z + x.w * x.w;
#pragma unroll
  for (int mask = 1; mask <= 32; mask <<= 1) {
    s += __shfl_xor(s, mask);
    ss += __shfl_xor(ss, mask);
  }
  __shared__ float as_[4], aq_[4];
  const int w = t >> 6;
  if ((t & 63) == 0) { as_[w] = s; aq_[w] = ss; }
  __syncthreads();
  s = as_[0] + as_[1] + as_[2] + as_[3];
  ss = aq_[0] + aq_[1] + aq_[2] + aq_[3];
  const float mu = s * (1.0f / 1024.0f);
  const float var = ss * (1.0f / 1024.0f) - mu * mu;
  const float inv = rsqrtf(var + LN_EPS);
  const float4 g4 = *(const float4*)&gamma[t * 4];
  const float4 b4 = *(const float4*)&beta[t * 4];
  float4 o;
  o.x = (x.x - mu) * inv * g4.x + b4.x;
  o.y = (x.y - mu) * inv * g4.y + b4.y;
  o.z = (x.z - mu) * inv * g4.z + b4.z;
  o.w = (x.w - mu) * inv * g4.w + b4.w;
  *(float4*)&out[(size_t)r * MD + t * 4] = o;
}

extern "C" void kernel_launch(void* const* d_in, const int* in_sizes, int n_in,
                              void* d_out, int out_size, void* d_ws,
                              size_t ws_size, hipStream_t stream) {
  (void)in_sizes; (void)n_in; (void)out_size; (void)ws_size;
  const float* key = (const float*)d_in[0];
  const float* value = (const float*)d_in[1];
  const float* query = (const float*)d_in[2];
  const float* rq = (const float*)d_in[3];
  const float* rv = (const float*)d_in[4];
  const float* Wq = (const float*)d_in[5];
  const float* bq = (const float*)d_in[6];
  const float* Wk = (const float*)d_in[7];
  const float* bk = (const float*)d_in[8];
  const float* Wv = (const float*)d_in[9];
  const float* bv = (const float*)d_in[10];
  const float* Wo = (const float*)d_in[11];
  const float* bo = (const float*)d_in[12];
  const float* gamma = (const float*)d_in[13];
  const float* beta = (const float*)d_in[14];

  float* out0 = (float*)d_out;               // [4,128,1024] = 524288 floats
  float* attn_out = (float*)d_out + 524288;  // [32,128,128] = 524288 floats

  float* ws = (float*)d_ws;
  float* q_ws = ws;                  // 524288 floats each
  float* k_ws = ws + 524288;
  float* v_ws = ws + 2 * 524288;
  float* v2_ws = ws + 3 * 524288;
  float* ctx_ws = ws + 4 * 524288;
  float* pre_ws = ws + 5 * 524288;

  qkv_gemm<<<dim3(8, 16, 3), 256, 0, stream>>>(query, key, value, Wq, Wk, Wv,
                                               bq, bk, bv, q_ws, k_ws, v_ws);
  rel_fused<<<dim3(32, 128), 256, 0, stream>>>(q_ws, k_ws, v_ws, rq, rv,
                                               attn_out, v2_ws);
  context_k<<<dim3(32, 128), 256, 0, stream>>>(attn_out, v2_ws, ctx_ws);
  o_gemm<<<dim3(8, 16), 256, 0, stream>>>(ctx_ws, Wo, bo, pre_ws);
  resid_ln<<<512, 256, 0, stream>>>(pre_ws, query, gamma, beta, out0);
}

// Round 2
// 277.123 us; speedup vs baseline: 1.0544x; 1.0544x over previous
//
#include <hip/hip_runtime.h>

#define MD 1024
#define L 128
#define BH 32
#define ROWS 512
#define LN_EPS 1e-5f

// ---------------------------------------------------------------------------
// Generic fp32 GEMM: out[r][c] = sum_m in[r][m] * W[c][m] + bias[c]
// (i.e. out = in @ W.T + bias). Tile 64x64, 256 threads, 4x4 per thread.
// ---------------------------------------------------------------------------
__device__ __forceinline__ void gemm_body(const float* __restrict__ in,
                                          const float* __restrict__ W,
                                          const float* __restrict__ bias,
                                          float* __restrict__ out) {
  __shared__ __align__(16) float As[64][36];
  __shared__ __align__(16) float Bs[64][36];
  const int t = threadIdx.x;
  const int row0 = blockIdx.x * 64;
  const int col0 = blockIdx.y * 64;
  const int tx = t & 15;
  const int ty = (t >> 4) & 15;
  float acc[4][4] = {{0.f, 0.f, 0.f, 0.f}, {0.f, 0.f, 0.f, 0.f},
                     {0.f, 0.f, 0.f, 0.f}, {0.f, 0.f, 0.f, 0.f}};
  const int lr0 = t >> 3;        // 0..31
  const int lk = (t & 7) * 4;    // 0,4,..,28

  for (int k0 = 0; k0 < MD; k0 += 32) {
    float4 a0 = *(const float4*)&in[(size_t)(row0 + lr0) * MD + k0 + lk];
    float4 a1 = *(const float4*)&in[(size_t)(row0 + lr0 + 32) * MD + k0 + lk];
    float4 b0 = *(const float4*)&W[(size_t)(col0 + lr0) * MD + k0 + lk];
    float4 b1 = *(const float4*)&W[(size_t)(col0 + lr0 + 32) * MD + k0 + lk];
    __syncthreads();
    *(float4*)&As[lr0][lk] = a0;
    *(float4*)&As[lr0 + 32][lk] = a1;
    *(float4*)&Bs[lr0][lk] = b0;
    *(float4*)&Bs[lr0 + 32][lk] = b1;
    __syncthreads();
#pragma unroll
    for (int kk = 0; kk < 32; kk++) {
      float a[4], b[4];
#pragma unroll
      for (int m = 0; m < 4; m++) a[m] = As[ty + 16 * m][kk];
#pragma unroll
      for (int n = 0; n < 4; n++) b[n] = Bs[tx + 16 * n][kk];
#pragma unroll
      for (int m = 0; m < 4; m++)
#pragma unroll
        for (int n = 0; n < 4; n++) acc[m][n] += a[m] * b[n];
    }
  }
#pragma unroll
  for (int m = 0; m < 4; m++) {
    const int rr = row0 + ty + 16 * m;
#pragma unroll
    for (int n = 0; n < 4; n++) {
      const int cc = col0 + tx + 16 * n;
      out[(size_t)rr * MD + cc] = acc[m][n] + bias[cc];
    }
  }
}

__global__ __launch_bounds__(256) void qkv_gemm(
    const float* __restrict__ query, const float* __restrict__ key,
    const float* __restrict__ value, const float* __restrict__ Wq,
    const float* __restrict__ Wk, const float* __restrict__ Wv,
    const float* __restrict__ bq, const float* __restrict__ bk,
    const float* __restrict__ bv, float* __restrict__ qo,
    float* __restrict__ ko, float* __restrict__ vo) {
  const float* in;
  const float* W;
  const float* bias;
  float* out;
  if (blockIdx.z == 0) { in = query; W = Wq; bias = bq; out = qo; }
  else if (blockIdx.z == 1) { in = key; W = Wk; bias = bk; out = ko; }
  else { in = value; W = Wv; bias = bv; out = vo; }
  gemm_body(in, W, bias, out);
}

__global__ __launch_bounds__(256) void o_gemm(const float* __restrict__ in,
                                              const float* __restrict__ W,
                                              const float* __restrict__ bias,
                                              float* __restrict__ out) {
  gemm_body(in, W, bias, out);
}

// ---------------------------------------------------------------------------
// Per (g, i): attn logits = q . (k + rq), softmax over j -> attn out;
// v2[g,i,j] = v[g,i,j] + v . rv[g,i,j,:]. Streams rq, rv (the 512 MB).
// Merged single loop: 3 independent load streams per iteration, explicit
// 2-deep register double-buffer (fully unrolled -> static indices), two
// interleaved shuffle-reduce chains. Keeps 3-6 loads in flight per wave.
// ---------------------------------------------------------------------------
__global__ __launch_bounds__(256) void rel_fused(
    const float* __restrict__ q, const float* __restrict__ k,
    const float* __restrict__ v, const float* __restrict__ rq,
    const float* __restrict__ rv, float* __restrict__ attn,
    float* __restrict__ v2) {
  const int g = blockIdx.x;  // 0..31
  const int i = blockIdx.y;  // 0..127
  const int t = threadIdx.x;
  const int w = t >> 6;
  const int l = t & 63;
  const int l32 = l & 31;
  const int half = l >> 5;
  __shared__ float logits[L];

  const size_t gi = (size_t)g * L + i;
  const float* qrow = q + (size_t)g * (L * 128) + (size_t)i * 128;
  const float* vrow = v + (size_t)g * (L * 128) + (size_t)i * 128;
  const float4 qf = *(const float4*)&qrow[l32 * 4];
  const float4 vf = *(const float4*)&vrow[l32 * 4];

  // row handled at step p: j(p) = w*32 + 2*p + half   (p = 0..15)
  const int jb = w * 32 + half;
  const float* rqp = rq + gi * (size_t)(L * 128) + (size_t)jb * 128 + l32 * 4;
  const float* rvp = rv + gi * (size_t)(L * 128) + (size_t)jb * 128 + l32 * 4;
  const float* kp = k + (size_t)g * (L * 128) + (size_t)jb * 128 + l32 * 4;

  float4 brq[2], bkk[2], brv[2];
  brq[0] = *(const float4*)&rqp[0];
  bkk[0] = *(const float4*)&kp[0];
  brv[0] = *(const float4*)&rvp[0];
  brq[1] = *(const float4*)&rqp[256];
  bkk[1] = *(const float4*)&kp[256];
  brv[1] = *(const float4*)&rvp[256];

#pragma unroll
  for (int p = 0; p < 16; ++p) {
    const int j = jb + 2 * p;
    const float4 rr = brq[p & 1];
    const float4 kk = bkk[p & 1];
    const float4 rv4 = brv[p & 1];
    float s = qf.x * (rr.x + kk.x) + qf.y * (rr.y + kk.y) +
              qf.z * (rr.z + kk.z) + qf.w * (rr.w + kk.w);
    float sv = vf.x * rv4.x + vf.y * rv4.y + vf.z * rv4.z + vf.w * rv4.w;
    if (p < 14) {  // prefetch p+2 into the slot just consumed
      brq[p & 1] = *(const float4*)&rqp[(size_t)(p + 2) * 256];
      bkk[p & 1] = *(const float4*)&kp[(size_t)(p + 2) * 256];
      brv[p & 1] = *(const float4*)&rvp[(size_t)(p + 2) * 256];
    }
    s += __shfl_xor(s, 1);
    sv += __shfl_xor(sv, 1);
    s += __shfl_xor(s, 2);
    sv += __shfl_xor(sv, 2);
    s += __shfl_xor(s, 4);
    sv += __shfl_xor(sv, 4);
    s += __shfl_xor(s, 8);
    sv += __shfl_xor(sv, 8);
    s += __shfl_xor(s, 16);
    sv += __shfl_xor(sv, 16);
    if (l32 == 0) {
      logits[j] = s * 0.25f;  // scale = (128//8)^-0.5 = 0.25
      v2[gi * 128 + j] = vrow[j] + sv;
    }
  }

  __syncthreads();
  if (w == 0) {
    const float x0 = logits[l];
    const float x1 = logits[l + 64];
    float m = fmaxf(x0, x1);
#pragma unroll
    for (int mask = 1; mask <= 32; mask <<= 1) m = fmaxf(m, __shfl_xor(m, mask));
    const float e0 = __expf(x0 - m);
    const float e1 = __expf(x1 - m);
    float ssum = e0 + e1;
#pragma unroll
    for (int mask = 1; mask <= 32; mask <<= 1) ssum += __shfl_xor(ssum, mask);
    const float inv = 1.0f / ssum;
    attn[gi * 128 + l] = e0 * inv;
    attn[gi * 128 + l + 64] = e1 * inv;
  }
}

// ---------------------------------------------------------------------------
// context[g,i,:] = sum_j attn[g,i,j] * v2[g,j,:]
// ---------------------------------------------------------------------------
__global__ __launch_bounds__(256) void context_k(const float* __restrict__ attn,
                                                 const float* __restrict__ v2,
                                                 float* __restrict__ ctx) {
  const int g = blockIdx.x;
  const int i = blockIdx.y;
  const int t = threadIdx.x;
  const int dd = t & 127;
  const int h = t >> 7;
  __shared__ float arow[L];
  __shared__ float part[128];
  const size_t gi = (size_t)g * L + i;
  if (t < L) arow[t] = attn[gi * 128 + t];
  __syncthreads();
  float acc = 0.f;
  const float* v2g = v2 + (size_t)g * (L * 128);
#pragma unroll 8
  for (int j = h * 64; j < h * 64 + 64; j++)
    acc = fmaf(arow[j], v2g[j * 128 + dd], acc);
  if (h == 1) part[dd] = acc;
  __syncthreads();
  if (h == 0) ctx[gi * 128 + dd] = acc + part[dd];
}

// ---------------------------------------------------------------------------
// out = LayerNorm(pre + residual) * gamma + beta, per row of 1024.
// ---------------------------------------------------------------------------
__global__ __launch_bounds__(256) void resid_ln(const float* __restrict__ pre,
                                                const float* __restrict__ resid,
                                                const float* __restrict__ gamma,
                                                const float* __restrict__ beta,
                                                float* __restrict__ out) {
  const int r = blockIdx.x;
  const int t = threadIdx.x;
  const float4 p = *(const float4*)&pre[(size_t)r * MD + t * 4];
  const float4 rs = *(const float4*)&resid[(size_t)r * MD + t * 4];
  float4 x;
  x.x = p.x + rs.x; x.y = p.y + rs.y; x.z = p.z + rs.z; x.w = p.w + rs.w;
  float s = x.x + x.y + x.z + x.w;
  float ss = x.x * x.x + x.y * x.y + x.z * x.z + x.w * x.w;
#pragma unroll
  for (int mask = 1; mask <= 32; mask <<= 1) {
    s += __shfl_xor(s, mask);
    ss += __shfl_xor(ss, mask);
  }
  __shared__ float as_[4], aq_[4];
  const int w = t >> 6;
  if ((t & 63) == 0) { as_[w] = s; aq_[w] = ss; }
  __syncthreads();
  s = as_[0] + as_[1] + as_[2] + as_[3];
  ss = aq_[0] + aq_[1] + aq_[2] + aq_[3];
  const float mu = s * (1.0f / 1024.0f);
  const float var = ss * (1.0f / 1024.0f) - mu * mu;
  const float inv = rsqrtf(var + LN_EPS);
  const float4 g4 = *(const float4*)&gamma[t * 4];
  const float4 b4 = *(const float4*)&beta[t * 4];
  float4 o;
  o.x = (x.x - mu) * inv * g4.x + b4.x;
  o.y = (x.y - mu) * inv * g4.y + b4.y;
  o.z = (x.z - mu) * inv * g4.z + b4.z;
  o.w = (x.w - mu) * inv * g4.w + b4.w;
  *(float4*)&out[(size_t)r * MD + t * 4] = o;
}

extern "C" void kernel_launch(void* const* d_in, const int* in_sizes, int n_in,
                              void* d_out, int out_size, void* d_ws,
                              size_t ws_size, hipStream_t stream) {
  (void)in_sizes; (void)n_in; (void)out_size; (void)ws_size;
  const float* key = (const float*)d_in[0];
  const float* value = (const float*)d_in[1];
  const float* query = (const float*)d_in[2];
  const float* rq = (const float*)d_in[3];
  const float* rv = (const float*)d_in[4];
  const float* Wq = (const float*)d_in[5];
  const float* bq = (const float*)d_in[6];
  const float* Wk = (const float*)d_in[7];
  const float* bk = (const float*)d_in[8];
  const float* Wv = (const float*)d_in[9];
  const float* bv = (const float*)d_in[10];
  const float* Wo = (const float*)d_in[11];
  const float* bo = (const float*)d_in[12];
  const float* gamma = (const float*)d_in[13];
  const float* beta = (const float*)d_in[14];

  float* out0 = (float*)d_out;               // [4,128,1024] = 524288 floats
  float* attn_out = (float*)d_out + 524288;  // [32,128,128] = 524288 floats

  float* ws = (float*)d_ws;
  float* q_ws = ws;                  // 524288 floats each
  float* k_ws = ws + 524288;
  float* v_ws = ws + 2 * 524288;
  float* v2_ws = ws + 3 * 524288;
  float* ctx_ws = ws + 4 * 524288;
  float* pre_ws = ws + 5 * 524288;

  qkv_gemm<<<dim3(8, 16, 3), 256, 0, stream>>>(query, key, value, Wq, Wk, Wv,
                                               bq, bk, bv, q_ws, k_ws, v_ws);
  rel_fused<<<dim3(32, 128), 256, 0, stream>>>(q_ws, k_ws, v_ws, rq, rv,
                                               attn_out, v2_ws);
  context_k<<<dim3(32, 128), 256, 0, stream>>>(attn_out, v2_ws, ctx_ws);
  o_gemm<<<dim3(8, 16), 256, 0, stream>>>(ctx_ws, Wo, bo, pre_ws);
  resid_ln<<<512, 256, 0, stream>>>(pre_ws, query, gamma, beta, out0);
}

// Round 3
// 272.282 us; speedup vs baseline: 1.0732x; 1.0178x over previous
//
#include <hip/hip_runtime.h>

#define MD 1024
#define L 128
#define BH 32
#define ROWS 512
#define LN_EPS 1e-5f

// ---------------------------------------------------------------------------
// Generic fp32 GEMM: out[r][c] = sum_m in[r][m] * W[c][m] + bias[c]
// (i.e. out = in @ W.T + bias). Tile 64x64, 256 threads, 4x4 per thread.
// ---------------------------------------------------------------------------
__device__ __forceinline__ void gemm_body(const float* __restrict__ in,
                                          const float* __restrict__ W,
                                          const float* __restrict__ bias,
                                          float* __restrict__ out) {
  __shared__ __align__(16) float As[64][36];
  __shared__ __align__(16) float Bs[64][36];
  const int t = threadIdx.x;
  const int row0 = blockIdx.x * 64;
  const int col0 = blockIdx.y * 64;
  const int tx = t & 15;
  const int ty = (t >> 4) & 15;
  float acc[4][4] = {{0.f, 0.f, 0.f, 0.f}, {0.f, 0.f, 0.f, 0.f},
                     {0.f, 0.f, 0.f, 0.f}, {0.f, 0.f, 0.f, 0.f}};
  const int lr0 = t >> 3;        // 0..31
  const int lk = (t & 7) * 4;    // 0,4,..,28

  for (int k0 = 0; k0 < MD; k0 += 32) {
    float4 a0 = *(const float4*)&in[(size_t)(row0 + lr0) * MD + k0 + lk];
    float4 a1 = *(const float4*)&in[(size_t)(row0 + lr0 + 32) * MD + k0 + lk];
    float4 b0 = *(const float4*)&W[(size_t)(col0 + lr0) * MD + k0 + lk];
    float4 b1 = *(const float4*)&W[(size_t)(col0 + lr0 + 32) * MD + k0 + lk];
    __syncthreads();
    *(float4*)&As[lr0][lk] = a0;
    *(float4*)&As[lr0 + 32][lk] = a1;
    *(float4*)&Bs[lr0][lk] = b0;
    *(float4*)&Bs[lr0 + 32][lk] = b1;
    __syncthreads();
#pragma unroll
    for (int kk = 0; kk < 32; kk++) {
      float a[4], b[4];
#pragma unroll
      for (int m = 0; m < 4; m++) a[m] = As[ty + 16 * m][kk];
#pragma unroll
      for (int n = 0; n < 4; n++) b[n] = Bs[tx + 16 * n][kk];
#pragma unroll
      for (int m = 0; m < 4; m++)
#pragma unroll
        for (int n = 0; n < 4; n++) acc[m][n] += a[m] * b[n];
    }
  }
#pragma unroll
  for (int m = 0; m < 4; m++) {
    const int rr = row0 + ty + 16 * m;
#pragma unroll
    for (int n = 0; n < 4; n++) {
      const int cc = col0 + tx + 16 * n;
      out[(size_t)rr * MD + cc] = acc[m][n] + bias[cc];
    }
  }
}

__global__ __launch_bounds__(256) void qkv_gemm(
    const float* __restrict__ query, const float* __restrict__ key,
    const float* __restrict__ value, const float* __restrict__ Wq,
    const float* __restrict__ Wk, const float* __restrict__ Wv,
    const float* __restrict__ bq, const float* __restrict__ bk,
    const float* __restrict__ bv, float* __restrict__ qo,
    float* __restrict__ ko, float* __restrict__ vo) {
  const float* in;
  const float* W;
  const float* bias;
  float* out;
  if (blockIdx.z == 0) { in = query; W = Wq; bias = bq; out = qo; }
  else if (blockIdx.z == 1) { in = key; W = Wk; bias = bk; out = ko; }
  else { in = value; W = Wv; bias = bv; out = vo; }
  gemm_body(in, W, bias, out);
}

__global__ __launch_bounds__(256) void o_gemm(const float* __restrict__ in,
                                              const float* __restrict__ W,
                                              const float* __restrict__ bias,
                                              float* __restrict__ out) {
  gemm_body(in, W, bias, out);
}

// ---------------------------------------------------------------------------
// rel_fused: per (g,i) block of 256 threads.
//   logits[j] = q . (k[g,j,:] + rq[g,i,j,:])   (scale applied in softmax)
//   v2[g,i,j] = v[g,i,j] + v . rv[g,i,j,:]
// Layout: 8 lanes per j-row (o = lane&7 owns float4 columns o, 8+o, 16+o,
// 24+o), 8 rows per wave per pass -> every load instruction is 8 x 128B
// contiguous segments. 3-level shuffle reduce. Explicit 2-deep prefetch
// (abuf/kbuf, static indices) pinned with sched_barrier(0) so the compiler
// cannot collapse the pipeline (round-1 failure: VGPR=36 proved collapse).
// ---------------------------------------------------------------------------
__global__ __launch_bounds__(256) void rel_fused(
    const float* __restrict__ q, const float* __restrict__ k,
    const float* __restrict__ v, const float* __restrict__ rq,
    const float* __restrict__ rv, float* __restrict__ attn,
    float* __restrict__ v2) {
  const int g = blockIdx.x;  // 0..31
  const int i = blockIdx.y;  // 0..127
  const int t = threadIdx.x;
  const int w = t >> 6;
  const int l = t & 63;
  const int r = l >> 3;  // row within wave's 8-row group
  const int o = l & 7;   // d-octant

  __shared__ float logits[L];
  __shared__ float vacc[L];
  __shared__ float vsh[L];

  const size_t gi = (size_t)g * L + i;
  const float* qrow = q + gi * 128;
  const float* vrow = v + gi * 128;
  if (t < 128) vsh[t] = vrow[t];

  float4 qr[4], vr[4];
#pragma unroll
  for (int m = 0; m < 4; m++) {
    qr[m] = *(const float4*)&qrow[(m * 8 + o) * 4];
    vr[m] = *(const float4*)&vrow[(m * 8 + o) * 4];
  }

  const int rbase = w * 8 + r;  // row within each 32-row pass group
  const float* rqp = rq + gi * 16384;
  const float* rvp = rv + gi * 16384;
  const float* kg = k + (size_t)g * 16384;
  const int coff = o * 4;  // lane's first float within its 4 columns

  float4 abuf[2][4], kbuf[2][4];
#pragma unroll
  for (int m = 0; m < 4; m++) {
    abuf[0][m] = *(const float4*)&rqp[(0 * 32 + rbase) * 128 + (m * 8) * 4 + coff];
    kbuf[0][m] = *(const float4*)&kg[(0 * 32 + rbase) * 128 + (m * 8) * 4 + coff];
  }
#pragma unroll
  for (int m = 0; m < 4; m++) {
    abuf[1][m] = *(const float4*)&rqp[(1 * 32 + rbase) * 128 + (m * 8) * 4 + coff];
    kbuf[1][m] = *(const float4*)&kg[(1 * 32 + rbase) * 128 + (m * 8) * 4 + coff];
  }
  __builtin_amdgcn_sched_barrier(0);

#pragma unroll
  for (int p = 0; p < 8; p++) {
    const int cur = p & 1;
    const int j = (p & 3) * 32 + rbase;
    float acc = 0.f;
    if (p < 4) {
#pragma unroll
      for (int m = 0; m < 4; m++) {
        acc += qr[m].x * (kbuf[cur][m].x + abuf[cur][m].x);
        acc += qr[m].y * (kbuf[cur][m].y + abuf[cur][m].y);
        acc += qr[m].z * (kbuf[cur][m].z + abuf[cur][m].z);
        acc += qr[m].w * (kbuf[cur][m].w + abuf[cur][m].w);
      }
    } else {
#pragma unroll
      for (int m = 0; m < 4; m++) {
        acc += vr[m].x * abuf[cur][m].x;
        acc += vr[m].y * abuf[cur][m].y;
        acc += vr[m].z * abuf[cur][m].z;
        acc += vr[m].w * abuf[cur][m].w;
      }
    }
    // prefetch pass p+2 into the slot just consumed (static after unroll)
    if (p + 2 < 8) {
      const int pp = p + 2;
      const float* base = (pp < 4) ? rqp : rvp;
      const int prow = ((pp & 3) * 32 + rbase) * 128;
#pragma unroll
      for (int m = 0; m < 4; m++)
        abuf[cur][m] = *(const float4*)&base[prow + (m * 8) * 4 + coff];
      if (pp < 4) {
#pragma unroll
        for (int m = 0; m < 4; m++)
          kbuf[cur][m] = *(const float4*)&kg[prow + (m * 8) * 4 + coff];
      }
    }
    __builtin_amdgcn_sched_barrier(0);
    acc += __shfl_xor(acc, 1);
    acc += __shfl_xor(acc, 2);
    acc += __shfl_xor(acc, 4);
    if (o == 0) {
      if (p < 4) logits[j] = acc;
      else vacc[j] = acc;
    }
  }

  __syncthreads();
  if (w == 0) {
    const float x0 = logits[l] * 0.25f;  // scale = (128//8)^-0.5
    const float x1 = logits[l + 64] * 0.25f;
    float m = fmaxf(x0, x1);
#pragma unroll
    for (int mask = 1; mask <= 32; mask <<= 1) m = fmaxf(m, __shfl_xor(m, mask));
    const float e0 = __expf(x0 - m);
    const float e1 = __expf(x1 - m);
    float ssum = e0 + e1;
#pragma unroll
    for (int mask = 1; mask <= 32; mask <<= 1) ssum += __shfl_xor(ssum, mask);
    const float inv = 1.0f / ssum;
    attn[gi * 128 + l] = e0 * inv;
    attn[gi * 128 + l + 64] = e1 * inv;
  }
  if (t < 128) v2[gi * 128 + t] = vsh[t] + vacc[t];
}

// ---------------------------------------------------------------------------
// context[g,i,:] = sum_j attn[g,i,j] * v2[g,j,:]
// ---------------------------------------------------------------------------
__global__ __launch_bounds__(256) void context_k(const float* __restrict__ attn,
                                                 const float* __restrict__ v2,
                                                 float* __restrict__ ctx) {
  const int g = blockIdx.x;
  const int i = blockIdx.y;
  const int t = threadIdx.x;
  const int dd = t & 127;
  const int h = t >> 7;
  __shared__ float arow[L];
  __shared__ float part[128];
  const size_t gi = (size_t)g * L + i;
  if (t < L) arow[t] = attn[gi * 128 + t];
  __syncthreads();
  float acc = 0.f;
  const float* v2g = v2 + (size_t)g * (L * 128);
#pragma unroll 8
  for (int j = h * 64; j < h * 64 + 64; j++)
    acc = fmaf(arow[j], v2g[j * 128 + dd], acc);
  if (h == 1) part[dd] = acc;
  __syncthreads();
  if (h == 0) ctx[gi * 128 + dd] = acc + part[dd];
}

// ---------------------------------------------------------------------------
// out = LayerNorm(pre + residual) * gamma + beta, per row of 1024.
// ---------------------------------------------------------------------------
__global__ __launch_bounds__(256) void resid_ln(const float* __restrict__ pre,
                                                const float* __restrict__ resid,
                                                const float* __restrict__ gamma,
                                                const float* __restrict__ beta,
                                                float* __restrict__ out) {
  const int r = blockIdx.x;
  const int t = threadIdx.x;
  const float4 p = *(const float4*)&pre[(size_t)r * MD + t * 4];
  const float4 rs = *(const float4*)&resid[(size_t)r * MD + t * 4];
  float4 x;
  x.x = p.x + rs.x; x.y = p.y + rs.y; x.z = p.z + rs.z; x.w = p.w + rs.w;
  float s = x.x + x.y + x.z + x.w;
  float ss = x.x * x.x + x.y * x.y + x.z * x.z + x.w * x.w;
#pragma unroll
  for (int mask = 1; mask <= 32; mask <<= 1) {
    s += __shfl_xor(s, mask);
    ss += __shfl_xor(ss, mask);
  }
  __shared__ float as_[4], aq_[4];
  const int w = t >> 6;
  if ((t & 63) == 0) { as_[w] = s; aq_[w] = ss; }
  __syncthreads();
  s = as_[0] + as_[1] + as_[2] + as_[3];
  ss = aq_[0] + aq_[1] + aq_[2] + aq_[3];
  const float mu = s * (1.0f / 1024.0f);
  const float var = ss * (1.0f / 1024.0f) - mu * mu;
  const float inv = rsqrtf(var + LN_EPS);
  const float4 g4 = *(const float4*)&gamma[t * 4];
  const float4 b4 = *(const float4*)&beta[t * 4];
  float4 o;
  o.x = (x.x - mu) * inv * g4.x + b4.x;
  o.y = (x.y - mu) * inv * g4.y + b4.y;
  o.z = (x.z - mu) * inv * g4.z + b4.z;
  o.w = (x.w - mu) * inv * g4.w + b4.w;
  *(float4*)&out[(size_t)r * MD + t * 4] = o;
}

extern "C" void kernel_launch(void* const* d_in, const int* in_sizes, int n_in,
                              void* d_out, int out_size, void* d_ws,
                              size_t ws_size, hipStream_t stream) {
  (void)in_sizes; (void)n_in; (void)out_size; (void)ws_size;
  const float* key = (const float*)d_in[0];
  const float* value = (const float*)d_in[1];
  const float* query = (const float*)d_in[2];
  const float* rq = (const float*)d_in[3];
  const float* rv = (const float*)d_in[4];
  const float* Wq = (const float*)d_in[5];
  const float* bq = (const float*)d_in[6];
  const float* Wk = (const float*)d_in[7];
  const float* bk = (const float*)d_in[8];
  const float* Wv = (const float*)d_in[9];
  const float* bv = (const float*)d_in[10];
  const float* Wo = (const float*)d_in[11];
  const float* bo = (const float*)d_in[12];
  const float* gamma = (const float*)d_in[13];
  const float* beta = (const float*)d_in[14];

  float* out0 = (float*)d_out;               // [4,128,1024] = 524288 floats
  float* attn_out = (float*)d_out + 524288;  // [32,128,128] = 524288 floats

  float* ws = (float*)d_ws;
  float* q_ws = ws;                  // 524288 floats each
  float* k_ws = ws + 524288;
  float* v_ws = ws + 2 * 524288;
  float* v2_ws = ws + 3 * 524288;
  float* ctx_ws = ws + 4 * 524288;
  float* pre_ws = ws + 5 * 524288;

  qkv_gemm<<<dim3(8, 16, 3), 256, 0, stream>>>(query, key, value, Wq, Wk, Wv,
                                               bq, bk, bv, q_ws, k_ws, v_ws);
  rel_fused<<<dim3(32, 128), 256, 0, stream>>>(q_ws, k_ws, v_ws, rq, rv,
                                               attn_out, v2_ws);
  context_k<<<dim3(32, 128), 256, 0, stream>>>(attn_out, v2_ws, ctx_ws);
  o_gemm<<<dim3(8, 16), 256, 0, stream>>>(ctx_ws, Wo, bo, pre_ws);
  resid_ln<<<512, 256, 0, stream>>>(pre_ws, query, gamma, beta, out0);
}

// Round 5
// 171.562 us; speedup vs baseline: 1.7032x; 1.5871x over previous
//
#include <hip/hip_runtime.h>

#define MD 1024
#define L 128
#define LN_EPS 1e-5f

typedef __attribute__((ext_vector_type(8))) short bh8;   // 8 x bf16 (4 VGPR)
typedef __attribute__((ext_vector_type(4))) float fx4;   // MFMA accumulator

__device__ __forceinline__ unsigned short f2bf(float x) {
  unsigned int u = __float_as_uint(x);
  u = (u + 0x7FFFu + ((u >> 16) & 1u)) >> 16;  // RNE
  return (unsigned short)u;
}

// ---------------------------------------------------------------------------
// fp32 -> bf16 convert: z picks array {query,key,value,Wq,Wk,Wv,Wo}
// ---------------------------------------------------------------------------
__global__ __launch_bounds__(256) void cvt_bf16(
    const float* s0, const float* s1, const float* s2, const float* s3,
    const float* s4, const float* s5, const float* s6, unsigned short* d0,
    unsigned short* d1, unsigned short* d2, unsigned short* d3,
    unsigned short* d4, unsigned short* d5, unsigned short* d6) {
  const float* s;
  unsigned short* d;
  int n;
  switch (blockIdx.z) {
    case 0: s = s0; d = d0; n = 524288; break;
    case 1: s = s1; d = d1; n = 524288; break;
    case 2: s = s2; d = d2; n = 524288; break;
    case 3: s = s3; d = d3; n = 1048576; break;
    case 4: s = s4; d = d4; n = 1048576; break;
    case 5: s = s5; d = d5; n = 1048576; break;
    default: s = s6; d = d6; n = 1048576; break;
  }
  const int idx = (blockIdx.x * 256 + threadIdx.x) * 8;
  if (idx < n) {
    const float4 a = *(const float4*)&s[idx];
    const float4 b = *(const float4*)&s[idx + 4];
    uint4 o;
    o.x = (unsigned int)f2bf(a.x) | ((unsigned int)f2bf(a.y) << 16);
    o.y = (unsigned int)f2bf(a.z) | ((unsigned int)f2bf(a.w) << 16);
    o.z = (unsigned int)f2bf(b.x) | ((unsigned int)f2bf(b.y) << 16);
    o.w = (unsigned int)f2bf(b.z) | ((unsigned int)f2bf(b.w) << 16);
    *(uint4*)&d[idx] = o;
  }
}

// ---------------------------------------------------------------------------
// bf16 MFMA GEMM: out[r][c] = sum_m A[r][m] * W[c][m] + bias[c]
// A: [512][1024] bf16, W: [1024][1024] bf16 (row = output col).
// 64x64 tile / block, 4 waves (2x2), each wave 32x32 via 2x2 16x16x32 frags.
// ---------------------------------------------------------------------------
__device__ __forceinline__ void mfma_gemm_body(
    const unsigned short* __restrict__ A, const unsigned short* __restrict__ W,
    const float* __restrict__ bias, float* __restrict__ out,
    unsigned short* __restrict__ outb) {
  __shared__ short As[64][40];
  __shared__ short Bs[64][40];
  const int t = threadIdx.x;
  const int row0 = blockIdx.x * 64;
  const int col0 = blockIdx.y * 64;
  const int l = t & 63;
  const int w = t >> 6;
  const int wr = (w >> 1) * 32;
  const int wc = (w & 1) * 32;
  const int srow = t >> 2;       // 0..63
  const int skg = (t & 3) * 8;   // 0,8,16,24
  const int fr = l & 15;
  const int fq = (l >> 4) * 8;

  fx4 z = {0.f, 0.f, 0.f, 0.f};
  fx4 acc[2][2];
  acc[0][0] = z; acc[0][1] = z; acc[1][0] = z; acc[1][1] = z;

  for (int k0 = 0; k0 < MD; k0 += 32) {
    const uint4 av = *(const uint4*)&A[(size_t)(row0 + srow) * MD + k0 + skg];
    const uint4 bv = *(const uint4*)&W[(size_t)(col0 + srow) * MD + k0 + skg];
    __syncthreads();
    *(uint4*)&As[srow][skg] = av;
    *(uint4*)&Bs[srow][skg] = bv;
    __syncthreads();
    const bh8 a0 = *(const bh8*)&As[wr + fr][fq];
    const bh8 a1 = *(const bh8*)&As[wr + 16 + fr][fq];
    const bh8 b0 = *(const bh8*)&Bs[wc + fr][fq];
    const bh8 b1 = *(const bh8*)&Bs[wc + 16 + fr][fq];
    acc[0][0] = __builtin_amdgcn_mfma_f32_16x16x32_bf16(a0, b0, acc[0][0], 0, 0, 0);
    acc[0][1] = __builtin_amdgcn_mfma_f32_16x16x32_bf16(a0, b1, acc[0][1], 0, 0, 0);
    acc[1][0] = __builtin_amdgcn_mfma_f32_16x16x32_bf16(a1, b0, acc[1][0], 0, 0, 0);
    acc[1][1] = __builtin_amdgcn_mfma_f32_16x16x32_bf16(a1, b1, acc[1][1], 0, 0, 0);
  }

  const int fq4 = (l >> 4) * 4;
#pragma unroll
  for (int m = 0; m < 2; m++)
#pragma unroll
    for (int n = 0; n < 2; n++) {
      const int col = col0 + wc + n * 16 + fr;
      const float bval = bias[col];
#pragma unroll
      for (int r = 0; r < 4; r++) {
        const int row = row0 + wr + m * 16 + fq4 + r;
        const float v = acc[m][n][r] + bval;
        if (out) out[(size_t)row * MD + col] = v;
        if (outb) outb[(size_t)row * MD + col] = f2bf(v);
      }
    }
}

__global__ __launch_bounds__(256) void qkv_mfma(
    const unsigned short* Aq, const unsigned short* Ak,
    const unsigned short* Av, const unsigned short* Wq,
    const unsigned short* Wk, const unsigned short* Wv, const float* bq,
    const float* bk, const float* bv, float* qo, float* ko, float* vo,
    unsigned short* qb, unsigned short* kb) {
  if (blockIdx.z == 0) mfma_gemm_body(Aq, Wq, bq, qo, qb);
  else if (blockIdx.z == 1) mfma_gemm_body(Ak, Wk, bk, ko, kb);
  else mfma_gemm_body(Av, Wv, bv, vo, nullptr);
}

__global__ __launch_bounds__(256) void o_mfma(const unsigned short* A,
                                              const unsigned short* W,
                                              const float* bias, float* out) {
  mfma_gemm_body(A, W, bias, out, nullptr);
}

// ---------------------------------------------------------------------------
// S1[g,i,j] = sum_d q[g,i,d]*k[g,j,d], one block per g.
// The .reshape(B*H,-1,d) view is FLAT: q[g][i][d] = qb_flat[g*16384+i*128+d],
// i.e. per-g a contiguous [128][128] bf16 tile at qb + g*16384.
// ---------------------------------------------------------------------------
__global__ __launch_bounds__(256) void qk_mfma(const unsigned short* __restrict__ qb,
                                               const unsigned short* __restrict__ kb,
                                               float* __restrict__ S1) {
  __shared__ short Qs[128][40];
  __shared__ short Ks[128][40];
  const int g = blockIdx.x;
  const int t = threadIdx.x;
  const int l = t & 63;
  const int w = t >> 6;
  const unsigned short* qg = qb + (size_t)g * 16384;
  const unsigned short* kg = kb + (size_t)g * 16384;
  const int srow = t >> 1;        // 0..127
  const int sh = (t & 1) * 16;    // 0 / 16
  const int fr = l & 15;
  const int fq = (l >> 4) * 8;

  fx4 z = {0.f, 0.f, 0.f, 0.f};
  fx4 acc[2][8];
#pragma unroll
  for (int m = 0; m < 2; m++)
#pragma unroll
    for (int n = 0; n < 8; n++) acc[m][n] = z;

  for (int d0 = 0; d0 < 128; d0 += 32) {
    const size_t off = (size_t)srow * 128 + d0 + sh;
    const uint4 q0 = *(const uint4*)&qg[off];
    const uint4 q1 = *(const uint4*)&qg[off + 8];
    const uint4 k0 = *(const uint4*)&kg[off];
    const uint4 k1 = *(const uint4*)&kg[off + 8];
    __syncthreads();
    *(uint4*)&Qs[srow][sh] = q0;
    *(uint4*)&Qs[srow][sh + 8] = q1;
    *(uint4*)&Ks[srow][sh] = k0;
    *(uint4*)&Ks[srow][sh + 8] = k1;
    __syncthreads();
    const bh8 a0 = *(const bh8*)&Qs[w * 32 + fr][fq];
    const bh8 a1 = *(const bh8*)&Qs[w * 32 + 16 + fr][fq];
#pragma unroll
    for (int n = 0; n < 8; n++) {
      const bh8 b = *(const bh8*)&Ks[n * 16 + fr][fq];
      acc[0][n] = __builtin_amdgcn_mfma_f32_16x16x32_bf16(a0, b, acc[0][n], 0, 0, 0);
      acc[1][n] = __builtin_amdgcn_mfma_f32_16x16x32_bf16(a1, b, acc[1][n], 0, 0, 0);
    }
  }

  const int fq4 = (l >> 4) * 4;
#pragma unroll
  for (int m = 0; m < 2; m++)
#pragma unroll
    for (int n = 0; n < 8; n++)
#pragma unroll
      for (int r = 0; r < 4; r++) {
        const int i = w * 32 + m * 16 + fq4 + r;
        S1[((size_t)g * 128 + i) * 128 + n * 16 + fr] = acc[m][n][r];
      }
}

// ---------------------------------------------------------------------------
// rel_fused: streams ONLY rq, rv (512 MB). logits[j] = q.rq[g,i,j,:];
// softmax over (S1 + logits)*0.25; v2[g,i,j] = v[g,i,j] + v.rv[g,i,j,:].
// 8 lanes per j-row, 8 rows/wave/pass, 2-deep pinned prefetch.
// ---------------------------------------------------------------------------
__global__ __launch_bounds__(256) void rel_fused(
    const float* __restrict__ q, const float* __restrict__ v,
    const float* __restrict__ rq, const float* __restrict__ rv,
    const float* __restrict__ S1, float* __restrict__ attn,
    float* __restrict__ v2) {
  const int g = blockIdx.x;
  const int i = blockIdx.y;
  const int t = threadIdx.x;
  const int w = t >> 6;
  const int l = t & 63;
  const int r = l >> 3;
  const int o = l & 7;

  __shared__ float logits[L];
  __shared__ float vacc[L];
  __shared__ float vsh[L];

  const size_t gi = (size_t)g * L + i;
  const float* qrow = q + gi * 128;
  const float* vrow = v + gi * 128;
  if (t < 128) vsh[t] = vrow[t];

  float4 qr[4], vr[4];
#pragma unroll
  for (int m = 0; m < 4; m++) {
    qr[m] = *(const float4*)&qrow[m * 32 + o * 4];
    vr[m] = *(const float4*)&vrow[m * 32 + o * 4];
  }

  const int rbase = w * 8 + r;
  const float* rqp = rq + gi * 16384;
  const float* rvp = rv + gi * 16384;
  const int coff = o * 4;

  float4 abuf[2][4];
#pragma unroll
  for (int m = 0; m < 4; m++)
    abuf[0][m] = *(const float4*)&rqp[rbase * 128 + m * 32 + coff];
#pragma unroll
  for (int m = 0; m < 4; m++)
    abuf[1][m] = *(const float4*)&rqp[(32 + rbase) * 128 + m * 32 + coff];
  __builtin_amdgcn_sched_barrier(0);

#pragma unroll
  for (int p = 0; p < 8; p++) {
    const int cur = p & 1;
    const int j = (p & 3) * 32 + rbase;
    float acc = 0.f;
    if (p < 4) {
#pragma unroll
      for (int m = 0; m < 4; m++) {
        acc += qr[m].x * abuf[cur][m].x;
        acc += qr[m].y * abuf[cur][m].y;
        acc += qr[m].z * abuf[cur][m].z;
        acc += qr[m].w * abuf[cur][m].w;
      }
    } else {
#pragma unroll
      for (int m = 0; m < 4; m++) {
        acc += vr[m].x * abuf[cur][m].x;
        acc += vr[m].y * abuf[cur][m].y;
        acc += vr[m].z * abuf[cur][m].z;
        acc += vr[m].w * abuf[cur][m].w;
      }
    }
    if (p + 2 < 8) {
      const int pp = p + 2;
      const float* base = (pp < 4) ? rqp : rvp;
      const int prow = ((pp & 3) * 32 + rbase) * 128;
#pragma unroll
      for (int m = 0; m < 4; m++)
        abuf[cur][m] = *(const float4*)&base[prow + m * 32 + coff];
    }
    __builtin_amdgcn_sched_barrier(0);
    acc += __shfl_xor(acc, 1);
    acc += __shfl_xor(acc, 2);
    acc += __shfl_xor(acc, 4);
    if (o == 0) {
      if (p < 4) logits[j] = acc;
      else vacc[j] = acc;
    }
  }

  __syncthreads();
  if (w == 0) {
    const float* S1p = S1 + gi * 128;
    const float x0 = (logits[l] + S1p[l]) * 0.25f;       // scale = 0.25
    const float x1 = (logits[l + 64] + S1p[l + 64]) * 0.25f;
    float m = fmaxf(x0, x1);
#pragma unroll
    for (int mask = 1; mask <= 32; mask <<= 1) m = fmaxf(m, __shfl_xor(m, mask));
    const float e0 = __expf(x0 - m);
    const float e1 = __expf(x1 - m);
    float ssum = e0 + e1;
#pragma unroll
    for (int mask = 1; mask <= 32; mask <<= 1) ssum += __shfl_xor(ssum, mask);
    const float inv = 1.0f / ssum;
    attn[gi * 128 + l] = e0 * inv;
    attn[gi * 128 + l + 64] = e1 * inv;
  }
  if (t < 128) v2[gi * 128 + t] = vsh[t] + vacc[t];
}

// ---------------------------------------------------------------------------
// ctx[g,i,:] = sum_j attn[g,i,j] * v2[g,j,:], written as bf16 FLAT
// (ctx_flat[gi*128+dd]) — identical memory layout to the [512][1024] view.
// ---------------------------------------------------------------------------
__global__ __launch_bounds__(256) void context_k(const float* __restrict__ attn,
                                                 const float* __restrict__ v2,
                                                 unsigned short* __restrict__ ctxb) {
  const int g = blockIdx.x;
  const int i = blockIdx.y;
  const int t = threadIdx.x;
  const int dd = t & 127;
  const int h = t >> 7;
  __shared__ float arow[L];
  __shared__ float part[128];
  const size_t gi = (size_t)g * L + i;
  if (t < L) arow[t] = attn[gi * 128 + t];
  __syncthreads();
  float acc = 0.f;
  const float* v2g = v2 + (size_t)g * (L * 128);
#pragma unroll 8
  for (int j = h * 64; j < h * 64 + 64; j++)
    acc = fmaf(arow[j], v2g[j * 128 + dd], acc);
  if (h == 1) part[dd] = acc;
  __syncthreads();
  if (h == 0) ctxb[gi * 128 + dd] = f2bf(acc + part[dd]);
}

// ---------------------------------------------------------------------------
// out = LayerNorm(pre + residual) * gamma + beta
// ---------------------------------------------------------------------------
__global__ __launch_bounds__(256) void resid_ln(const float* __restrict__ pre,
                                                const float* __restrict__ resid,
                                                const float* __restrict__ gamma,
                                                const float* __restrict__ beta,
                                                float* __restrict__ out) {
  const int r = blockIdx.x;
  const int t = threadIdx.x;
  const float4 p = *(const float4*)&pre[(size_t)r * MD + t * 4];
  const float4 rs = *(const float4*)&resid[(size_t)r * MD + t * 4];
  float4 x;
  x.x = p.x + rs.x; x.y = p.y + rs.y; x.z = p.z + rs.z; x.w = p.w + rs.w;
  float s = x.x + x.y + x.z + x.w;
  float ss = x.x * x.x + x.y * x.y + x.z * x.z + x.w * x.w;
#pragma unroll
  for (int mask = 1; mask <= 32; mask <<= 1) {
    s += __shfl_xor(s, mask);
    ss += __shfl_xor(ss, mask);
  }
  __shared__ float as_[4], aq_[4];
  const int w = t >> 6;
  if ((t & 63) == 0) { as_[w] = s; aq_[w] = ss; }
  __syncthreads();
  s = as_[0] + as_[1] + as_[2] + as_[3];
  ss = aq_[0] + aq_[1] + aq_[2] + aq_[3];
  const float mu = s * (1.0f / 1024.0f);
  const float var = ss * (1.0f / 1024.0f) - mu * mu;
  const float inv = rsqrtf(var + LN_EPS);
  const float4 g4 = *(const float4*)&gamma[t * 4];
  const float4 b4 = *(const float4*)&beta[t * 4];
  float4 o;
  o.x = (x.x - mu) * inv * g4.x + b4.x;
  o.y = (x.y - mu) * inv * g4.y + b4.y;
  o.z = (x.z - mu) * inv * g4.z + b4.z;
  o.w = (x.w - mu) * inv * g4.w + b4.w;
  *(float4*)&out[(size_t)r * MD + t * 4] = o;
}

extern "C" void kernel_launch(void* const* d_in, const int* in_sizes, int n_in,
                              void* d_out, int out_size, void* d_ws,
                              size_t ws_size, hipStream_t stream) {
  (void)in_sizes; (void)n_in; (void)out_size; (void)ws_size;
  const float* key = (const float*)d_in[0];
  const float* value = (const float*)d_in[1];
  const float* query = (const float*)d_in[2];
  const float* rq = (const float*)d_in[3];
  const float* rv = (const float*)d_in[4];
  const float* Wq = (const float*)d_in[5];
  const float* bq = (const float*)d_in[6];
  const float* Wk = (const float*)d_in[7];
  const float* bk = (const float*)d_in[8];
  const float* Wv = (const float*)d_in[9];
  const float* bv = (const float*)d_in[10];
  const float* Wo = (const float*)d_in[11];
  const float* bo = (const float*)d_in[12];
  const float* gamma = (const float*)d_in[13];
  const float* beta = (const float*)d_in[14];

  float* out0 = (float*)d_out;               // [4,128,1024]
  float* attn_out = (float*)d_out + 524288;  // [32,128,128]

  float* ws = (float*)d_ws;
  float* q_ws = ws;                    // fp32 [512][1024]
  float* k_ws = ws + 524288;           // (unused fp32 k — kept for layout)
  float* v_ws = ws + 2 * 524288;
  float* v2_ws = ws + 3 * 524288;
  float* pre_ws = ws + 4 * 524288;
  float* S1_ws = ws + 5 * 524288;      // [32][128][128] fp32
  unsigned short* us = (unsigned short*)(ws + 6 * 524288);
  unsigned short* qb = us;             // bf16 [512][1024] each
  unsigned short* kb = us + 524288;
  unsigned short* inqb = us + 2 * 524288;
  unsigned short* inkb = us + 3 * 524288;
  unsigned short* invb = us + 4 * 524288;
  unsigned short* ctxb = us + 5 * 524288;
  unsigned short* Wqb = us + 6 * 524288;   // bf16 [1024][1024] each
  unsigned short* Wkb = Wqb + 1048576;
  unsigned short* Wvb = Wkb + 1048576;
  unsigned short* Wob = Wvb + 1048576;

  cvt_bf16<<<dim3(512, 1, 7), 256, 0, stream>>>(query, key, value, Wq, Wk, Wv,
                                                Wo, inqb, inkb, invb, Wqb, Wkb,
                                                Wvb, Wob);
  qkv_mfma<<<dim3(8, 16, 3), 256, 0, stream>>>(inqb, inkb, invb, Wqb, Wkb, Wvb,
                                               bq, bk, bv, q_ws, k_ws, v_ws,
                                               qb, kb);
  qk_mfma<<<32, 256, 0, stream>>>(qb, kb, S1_ws);
  rel_fused<<<dim3(32, 128), 256, 0, stream>>>(q_ws, v_ws, rq, rv, S1_ws,
                                               attn_out, v2_ws);
  context_k<<<dim3(32, 128), 256, 0, stream>>>(attn_out, v2_ws, ctxb);
  o_mfma<<<dim3(8, 16), 256, 0, stream>>>(ctxb, Wob, bo, pre_ws);
  resid_ln<<<512, 256, 0, stream>>>(pre_ws, query, gamma, beta, out0);
}